// Round 6
// baseline (114.973 us; speedup 1.0000x reference)
//
#include <hip/hip_runtime.h>
#include <hip/hip_bf16.h>
#include <cstdint>

// Problem constants
#define NWORDS 16384   // B*S
#define NCH    20      // chars per word
#define CEDIM  32      // char emb dim
#define WEDIM  512     // output channels
#define WPB    32      // words per block
#define NBLK   (NWORDS/WPB)   // 512

#define AS3 __attribute__((address_space(3)))
#define AS1 __attribute__((address_space(1)))

typedef __attribute__((ext_vector_type(8))) short bf16x8;
typedef __attribute__((ext_vector_type(4))) float f32x4;

__device__ __forceinline__ unsigned short f2bf(float f){
    union { float f; unsigned int u; } v; v.f = f;
    unsigned int u = v.u + 0x7fffu + ((v.u >> 16) & 1u);
    return (unsigned short)(u >> 16);
}

// Prep (unchanged from round 5):
//  wbf2[((cc*16+kc)*64+col)*8 + j] = bf16(cnn[o=cc*64+col][i][k]), kk=kc*8+j=k*32+i
//  cembbf: [257][32] bf16, row 256 = zeros; bias[o] = sum_k cnn[o][32][k]
__global__ __launch_bounds__(256) void prep_kernel(const float* __restrict__ cnn,
                                                   const float* __restrict__ cemb,
                                                   unsigned short* __restrict__ wbf2,
                                                   unsigned short* __restrict__ cembbf,
                                                   float* __restrict__ bias){
    int idx = blockIdx.x * 256 + threadIdx.x;
    if (idx < 65536){
        int j  = idx & 7;
        int col= (idx >> 3) & 63;
        int kc = (idx >> 9) & 15;
        int cc = idx >> 13;
        int o  = cc*64 + col;
        int kk = kc*8 + j;
        int i  = kk & 31, k = kk >> 5;
        wbf2[idx] = f2bf(cnn[o*132 + i*4 + k]);
    } else if (idx < 65536 + 257*CEDIM){
        int r = idx - 65536;
        cembbf[r] = (r < 256*CEDIM) ? f2bf(cemb[r]) : (unsigned short)0;
    } else if (idx < 65536 + 257*CEDIM + WEDIM){
        int o = idx - (65536 + 257*CEDIM);
        const float* p = cnn + o*132 + 128;
        bias[o] = p[0] + p[1] + p[2] + p[3];
    }
}

// 512 threads (8 waves x 4 words), sW = 2 buffers x 2 cc-chunks = 64 KB static.
// 4 barriers/block (vs round 5's 8 for half the words). Char ids gathered
// directly from global (L1-hot) -- no scid LDS, no barrier before A-gathers.
// waves_per_eu(2,2): round 4 proved forcing higher occupancy spills ~100 MB.
__global__ __attribute__((amdgpu_waves_per_eu(2,2))) __launch_bounds__(512)
void conv_kernel(
    const int* __restrict__ data,              // [16384]
    const int* __restrict__ spelling,          // [50000][20]
    const unsigned short* __restrict__ cembbf, // [257][32] bf16 (row 256 = 0)
    const unsigned short* __restrict__ wbf2,   // [8][16][64][8] bf16 k-major
    const float* __restrict__ bias,            // [512]
    float* __restrict__ out)                   // [16384][512] f32
{
    __shared__ __align__(16) unsigned short sW[2][16384];  // 2 x 32 KB (2 cc each)

    const int tid   = threadIdx.x;
    const int wv    = tid >> 6;       // wave 0..7, owns words wv*4..wv*4+3
    const int lane  = tid & 63;
    const int lr    = lane & 15, lq = lane >> 4;
    const int lqoff = lq * 16;
    const int wbase = blockIdx.x * WPB;

    // ---- stage pair 0 (cc 0,1) into sW[0]: 32 KB, 4 x 1 KB per wave ----
    #pragma unroll
    for (int t = 0; t < 4; ++t){
        int c = t*8 + wv;                       // 1 KB chunk 0..31
        const unsigned short* gp = wbf2 + c*512 + lane*8;
        unsigned short* lp = &sW[0][c*512];
        __builtin_amdgcn_global_load_lds((const AS1 void*)gp, (AS3 void*)lp, 16, 0, 0);
    }

    const char* cb = (const char*)cembbf;

    // ---- A fragments, resident (gathered straight from global) ----
    // lane (lr,lq) holds A[m=t=lr][kk'=q*32+lq*8+j] = cemb[spell[wd][lr+q]][lq*8+j]
    bf16x8 af[4][4];
    #pragma unroll
    for (int mi = 0; mi < 4; ++mi){
        int wd = data[wbase + wv*4 + mi];
        const int* sp = spelling + wd*NCH + lr;
        #pragma unroll
        for (int q = 0; q < 4; ++q)
            af[mi][q] = *reinterpret_cast<const bf16x8*>(cb + sp[q]*64 + lqoff);
    }
    // t=16 tile: rows 0..3 = this wave's words, rows 4..15 -> zero row 256
    bf16x8 axf[4];
    {
        int wdx = data[wbase + wv*4 + (lr & 3)];
        #pragma unroll
        for (int q = 0; q < 4; ++q){
            int ch = (lr < 4) ? spelling[wdx*NCH + 16 + q] : 256;
            axf[q] = *reinterpret_cast<const bf16x8*>(cb + ch*64 + lqoff);
        }
    }

    __syncthreads();   // stage 0 landed

    #pragma unroll 1
    for (int p = 0; p < 4; ++p){
        const int cur = p & 1, nxt = cur ^ 1;

        // prefetch next cc-pair (overlaps 160 MFMAs + 2 epilogues)
        if (p < 3){
            #pragma unroll
            for (int t = 0; t < 4; ++t){
                int c = t*8 + wv;
                const unsigned short* gp = wbf2 + (p+1)*16384 + c*512 + lane*8;
                unsigned short* lp = &sW[nxt][c*512];
                __builtin_amdgcn_global_load_lds((const AS1 void*)gp, (AS3 void*)lp, 16, 0, 0);
            }
        }

        #pragma unroll
        for (int ccl = 0; ccl < 2; ++ccl){
            const int cc = p*2 + ccl;

            f32x4 acc[4][4], accX[4];
            {
                f32x4 z = {0.f, 0.f, 0.f, 0.f};
                #pragma unroll
                for (int ni = 0; ni < 4; ++ni){
                    accX[ni] = z;
                    #pragma unroll
                    for (int mi = 0; mi < 4; ++mi) acc[mi][ni] = z;
                }
            }

            #pragma unroll
            for (int q = 0; q < 4; ++q){
                // B frag: col = ni*16+lr, kc = q*4+lq, k-major [kc][col][8]
                const unsigned short* wl = &sW[cur][ccl*8192 + (q*4 + lq)*512 + lr*8];
                bf16x8 bb[4];
                #pragma unroll
                for (int ni = 0; ni < 4; ++ni)
                    bb[ni] = *reinterpret_cast<const bf16x8*>(wl + ni*128);
                #pragma unroll
                for (int ni = 0; ni < 4; ++ni){
                    #pragma unroll
                    for (int mi = 0; mi < 4; ++mi)
                        acc[mi][ni] = __builtin_amdgcn_mfma_f32_16x16x32_bf16(
                            af[mi][q], bb[ni], acc[mi][ni], 0, 0, 0);
                    accX[ni] = __builtin_amdgcn_mfma_f32_16x16x32_bf16(
                            axf[q], bb[ni], accX[ni], 0, 0, 0);
                }
            }

            // epilogue: per word, max over t (regs + 2 shfl), coalesced store
            float bv = bias[cc*64 + lane];
            #pragma unroll
            for (int mi = 0; mi < 4; ++mi){
                float mred[4];
                #pragma unroll
                for (int ni = 0; ni < 4; ++ni){
                    float m = fmaxf(fmaxf(acc[mi][ni][0], acc[mi][ni][1]),
                                    fmaxf(acc[mi][ni][2], acc[mi][ni][3]));
                    // t=16: word mi lives at lanes lq==0, reg mi of accX
                    if (lq == 0) m = fmaxf(m, accX[ni][mi]);
                    m = fmaxf(m, __shfl_xor(m, 16, 64));
                    m = fmaxf(m, __shfl_xor(m, 32, 64));
                    mred[ni] = m;
                }
                float mv = (lq == 0) ? mred[0] : (lq == 1) ? mred[1]
                         : (lq == 2) ? mred[2] : mred[3];
                __builtin_nontemporal_store(
                    mv + bv, &out[(wbase + wv*4 + mi)*WEDIM + cc*64 + lane]);
            }
        }

        if (p < 3) __syncthreads();   // staging of nxt done; cur free
    }
}

extern "C" void kernel_launch(void* const* d_in, const int* in_sizes, int n_in,
                              void* d_out, int out_size, void* d_ws, size_t ws_size,
                              hipStream_t stream) {
    const float* cemb     = (const float*)d_in[0];   // char_emb_w [256*32]
    const float* cnn      = (const float*)d_in[1];   // cnn_w [512*33*4]
    const int*   data     = (const int*)d_in[2];     // [16384]
    const int*   spelling = (const int*)d_in[3];     // [50000*20]
    float* outp = (float*)d_out;

    unsigned short* wbf2   = (unsigned short*)d_ws;                       // 131072 B
    float*          bias   = (float*)((char*)d_ws + 131072);              // 2048 B
    unsigned short* cembbf = (unsigned short*)((char*)d_ws + 133120);     // 16448 B

    int prep_items = 65536 + 257*CEDIM + WEDIM;   // 74272
    prep_kernel<<<dim3((prep_items + 255)/256), dim3(256), 0, stream>>>(cnn, cemb, wbf2, cembbf, bias);
    conv_kernel<<<dim3(NBLK), dim3(512), 0, stream>>>(data, spelling, cembbf, wbf2, bias, outp);
}

// Round 7
// 107.682 us; speedup vs baseline: 1.0677x; 1.0677x over previous
//
#include <hip/hip_runtime.h>
#include <hip/hip_bf16.h>
#include <cstdint>

// Problem constants
#define NWORDS 16384   // B*S
#define NCH    20      // chars per word
#define CEDIM  32      // char emb dim
#define WEDIM  512     // output channels
#define WPB    16      // words per block
#define NBLK   (NWORDS/WPB)   // 1024

#define AS3 __attribute__((address_space(3)))
#define AS1 __attribute__((address_space(1)))

typedef __attribute__((ext_vector_type(8))) short bf16x8;
typedef __attribute__((ext_vector_type(4))) float f32x4;

__device__ __forceinline__ unsigned short f2bf(float f){
    union { float f; unsigned int u; } v; v.f = f;
    unsigned int u = v.u + 0x7fffu + ((v.u >> 16) & 1u);
    return (unsigned short)(u >> 16);
}

// Prep (unchanged, verified rounds 5-6):
//  wbf2[((cc*16+kc)*64+col)*8 + j] = bf16(cnn[o=cc*64+col][i][k]), kk=kc*8+j=k*32+i
//  cembbf: [257][32] bf16, row 256 = zeros; bias[o] = sum_k cnn[o][32][k]
__global__ __launch_bounds__(256) void prep_kernel(const float* __restrict__ cnn,
                                                   const float* __restrict__ cemb,
                                                   unsigned short* __restrict__ wbf2,
                                                   unsigned short* __restrict__ cembbf,
                                                   float* __restrict__ bias){
    int idx = blockIdx.x * 256 + threadIdx.x;
    if (idx < 65536){
        int j  = idx & 7;
        int col= (idx >> 3) & 63;
        int kc = (idx >> 9) & 15;
        int cc = idx >> 13;
        int o  = cc*64 + col;
        int kk = kc*8 + j;
        int i  = kk & 31, k = kk >> 5;
        wbf2[idx] = f2bf(cnn[o*132 + i*4 + k]);
    } else if (idx < 65536 + 257*CEDIM){
        int r = idx - 65536;
        cembbf[r] = (r < 256*CEDIM) ? f2bf(cemb[r]) : (unsigned short)0;
    } else if (idx < 65536 + 257*CEDIM + WEDIM){
        int o = idx - (65536 + 257*CEDIM);
        const float* p = cnn + o*132 + 128;
        bias[o] = p[0] + p[1] + p[2] + p[3];
    }
}

// Round 7: pair-packed M-tiles (2 words x 8 t's per 16-row tile) -> 1 shfl
// per output (was 2); ni-blocked (2x32-col passes) -> 40 AGPR; ~150 unified
// regs -> 3 waves/SIMD via waves_per_eu(3). 256 threads, 4 waves x 4 words.
__global__ __attribute__((amdgpu_waves_per_eu(3))) __launch_bounds__(256)
void conv_kernel(
    const int* __restrict__ data,              // [16384]
    const int* __restrict__ spelling,          // [50000][20]
    const unsigned short* __restrict__ cembbf, // [257][32] bf16 (row 256 = 0)
    const unsigned short* __restrict__ wbf2,   // [8][16][64][8] bf16 k-major
    const float* __restrict__ bias,            // [512]
    float* __restrict__ out)                   // [16384][512] f32
{
    __shared__ __align__(16) unsigned short sW[2][8192];  // 2 x 16 KB cc-tiles

    const int tid   = threadIdx.x;
    const int wv    = tid >> 6;       // wave 0..3, owns words wv*4..wv*4+3
    const int lane  = tid & 63;
    const int lr    = lane & 15, lq = lane >> 4;
    const int lqoff = lq * 16;        // byte offset into a 64 B emb row
    const int wbase = blockIdx.x * WPB;

    // ---- stage cc=0 tile (16 KB, 4 x 1 KB per wave) ----
    #pragma unroll
    for (int t = 0; t < 4; ++t){
        int slot = wv*4 + t;
        const unsigned short* gp = wbf2 + slot*512 + lane*8;
        unsigned short* lp = &sW[0][slot*512];
        __builtin_amdgcn_global_load_lds((const AS1 void*)gp, (AS3 void*)lp, 16, 0, 0);
    }

    const char* cb = (const char*)cembbf;

    // ---- A fragments: pair-packed tiles ----
    // tile (p,h): rows 0-7 = word wv*4+2p,   t = h*8 + row
    //             rows 8-15 = word wv*4+2p+1, t = h*8 + (row-8)
    // lane (lr,lq) holds A[m=lr][kk'=q*32+lq*8+j] = cemb[spell[wd][h*8+(lr&7)+q]]
    bf16x8 af[2][2][4];   // [pair][h][q]
    #pragma unroll
    for (int p = 0; p < 2; ++p){
        int wd = data[wbase + wv*4 + 2*p + (lr >> 3)];
        const int* sp = spelling + wd*NCH;
        #pragma unroll
        for (int h = 0; h < 2; ++h){
            int b = h*8 + (lr & 7);
            #pragma unroll
            for (int q = 0; q < 4; ++q)
                af[p][h][q] = *reinterpret_cast<const bf16x8*>(cb + sp[b+q]*64 + lqoff);
        }
    }
    // t=16 tile: word 2p+s -> row s*8+p (rows 0,1,8,9); others -> zero row 256
    bf16x8 axf[4];
    {
        bool valid = (lr & 7) < 2;
        int wloc = 2*(lr & 7) + (lr >> 3);
        int wdx = data[wbase + wv*4 + (valid ? wloc : 0)];
        #pragma unroll
        for (int q = 0; q < 4; ++q){
            int ch = valid ? spelling[wdx*NCH + 16 + q] : 256;
            axf[q] = *reinterpret_cast<const bf16x8*>(cb + ch*64 + lqoff);
        }
    }

    __syncthreads();   // stage 0 landed

    #pragma unroll 1
    for (int cc = 0; cc < 8; ++cc){
        const int cur = cc & 1, nxt = cur ^ 1;

        // prefetch next cc tile (overlaps 160 MFMAs + epilogues)
        if (cc < 7){
            #pragma unroll
            for (int t = 0; t < 4; ++t){
                int slot = wv*4 + t;
                const unsigned short* gp = wbf2 + (cc+1)*8192 + slot*512 + lane*8;
                unsigned short* lp = &sW[nxt][slot*512];
                __builtin_amdgcn_global_load_lds((const AS1 void*)gp, (AS3 void*)lp, 16, 0, 0);
            }
        }

        #pragma unroll
        for (int n = 0; n < 2; ++n){   // 32-col half of the cc chunk
            f32x4 acc[8], accX[2];     // acc[(p*2+h)*2+nl]
            {
                f32x4 z = {0.f, 0.f, 0.f, 0.f};
                #pragma unroll
                for (int i = 0; i < 8; ++i) acc[i] = z;
                accX[0] = z; accX[1] = z;
            }

            #pragma unroll
            for (int q = 0; q < 4; ++q){
                // B frag: col = n*32 + nl*16 + lr, kc = q*4+lq, k-major layout
                const unsigned short* wl = &sW[cur][(q*4 + lq)*512 + (n*32 + lr)*8];
                bf16x8 bb0 = *reinterpret_cast<const bf16x8*>(wl);
                bf16x8 bb1 = *reinterpret_cast<const bf16x8*>(wl + 128);
                #pragma unroll
                for (int p = 0; p < 2; ++p)
                    #pragma unroll
                    for (int h = 0; h < 2; ++h){
                        acc[(p*2+h)*2+0] = __builtin_amdgcn_mfma_f32_16x16x32_bf16(
                            af[p][h][q], bb0, acc[(p*2+h)*2+0], 0, 0, 0);
                        acc[(p*2+h)*2+1] = __builtin_amdgcn_mfma_f32_16x16x32_bf16(
                            af[p][h][q], bb1, acc[(p*2+h)*2+1], 0, 0, 0);
                    }
                accX[0] = __builtin_amdgcn_mfma_f32_16x16x32_bf16(axf[q], bb0, accX[0], 0, 0, 0);
                accX[1] = __builtin_amdgcn_mfma_f32_16x16x32_bf16(axf[q], bb1, accX[1], 0, 0, 0);
            }

            // ---- epilogue: 1 shfl per output ----
            // C rows: lq*4+reg. Lanes lq0,1 hold word 2p (t = h*8+{lq*4..+3}),
            // lanes lq2,3 hold word 2p+1. accX: word 2p+s at lq=s*2, reg=p.
            #pragma unroll
            for (int p = 0; p < 2; ++p){
                float m[2];
                #pragma unroll
                for (int nl = 0; nl < 2; ++nl){
                    f32x4 a0 = acc[(p*2+0)*2+nl];
                    f32x4 a1 = acc[(p*2+1)*2+nl];
                    float v = fmaxf(fmaxf(fmaxf(a0[0], a0[1]), fmaxf(a0[2], a0[3])),
                                    fmaxf(fmaxf(a1[0], a1[1]), fmaxf(a1[2], a1[3])));
                    if ((lq & 1) == 0) v = fmaxf(v, accX[nl][p]);   // fold t=16
                    v = fmaxf(v, __shfl_xor(v, 16, 64));            // lq0<->1, lq2<->3
                    m[nl] = v;
                }
                int col  = cc*64 + n*32 + (lq & 1)*16 + lr;
                int word = wbase + wv*4 + 2*p + (lq >> 1);
                float mv = (lq & 1) ? m[1] : m[0];
                __builtin_nontemporal_store(mv + bias[col], &out[word*WEDIM + col]);
            }
        }

        if (cc < 7) __syncthreads();   // prefetch landed; cur buffer free
    }
}

extern "C" void kernel_launch(void* const* d_in, const int* in_sizes, int n_in,
                              void* d_out, int out_size, void* d_ws, size_t ws_size,
                              hipStream_t stream) {
    const float* cemb     = (const float*)d_in[0];   // char_emb_w [256*32]
    const float* cnn      = (const float*)d_in[1];   // cnn_w [512*33*4]
    const int*   data     = (const int*)d_in[2];     // [16384]
    const int*   spelling = (const int*)d_in[3];     // [50000*20]
    float* outp = (float*)d_out;

    unsigned short* wbf2   = (unsigned short*)d_ws;                       // 131072 B
    float*          bias   = (float*)((char*)d_ws + 131072);              // 2048 B
    unsigned short* cembbf = (unsigned short*)((char*)d_ws + 133120);     // 16448 B

    int prep_items = 65536 + 257*CEDIM + WEDIM;   // 74272
    prep_kernel<<<dim3((prep_items + 255)/256), dim3(256), 0, stream>>>(cnn, cemb, wbf2, cembbf, bias);
    conv_kernel<<<dim3(NBLK), dim3(256), 0, stream>>>(data, spelling, cembbf, wbf2, bias, outp);
}